// Round 3
// baseline (348.895 us; speedup 1.0000x reference)
//
#include <hip/hip_runtime.h>

typedef _Float16 f16;
typedef _Float16 f16x8 __attribute__((ext_vector_type(8)));
typedef float    f32x4 __attribute__((ext_vector_type(4)));

#define NROWS 65536
#define DDIM  512
#define BM    128     // rows per block = one ghost batch
#define ZP    516     // zbuf row pitch (floats): 2064 B -> bank-spread reads

// ---- DPP wave-64 reductions: short dependent chain, uniform result ---------
template <int CTRL, int RM>
__device__ __forceinline__ float dpp_mov_f(float src, float old) {
  return __int_as_float(__builtin_amdgcn_update_dpp(
      __float_as_int(old), __float_as_int(src), CTRL, RM, 0xf, false));
}
__device__ __forceinline__ float dpp_sum64(float x) {
  x += dpp_mov_f<0x121, 0xf>(x, 0.f);   // row_ror:1
  x += dpp_mov_f<0x122, 0xf>(x, 0.f);   // row_ror:2
  x += dpp_mov_f<0x124, 0xf>(x, 0.f);   // row_ror:4
  x += dpp_mov_f<0x128, 0xf>(x, 0.f);   // row_ror:8  -> each lane: row sum
  x += dpp_mov_f<0x142, 0xa>(x, 0.f);   // bcast15 -> rows 1,3
  x += dpp_mov_f<0x143, 0xc>(x, 0.f);   // bcast31 -> lane63 = total
  return __int_as_float(__builtin_amdgcn_readlane(__float_as_int(x), 63));
}
__device__ __forceinline__ float dpp_max64(float x) {
  x = fmaxf(x, dpp_mov_f<0x121, 0xf>(x, -1e30f));
  x = fmaxf(x, dpp_mov_f<0x122, 0xf>(x, -1e30f));
  x = fmaxf(x, dpp_mov_f<0x124, 0xf>(x, -1e30f));
  x = fmaxf(x, dpp_mov_f<0x128, 0xf>(x, -1e30f));
  x = fmaxf(x, dpp_mov_f<0x142, 0xa>(x, -1e30f));
  x = fmaxf(x, dpp_mov_f<0x143, 0xc>(x, -1e30f));
  return __int_as_float(__builtin_amdgcn_readlane(__float_as_int(x), 63));
}

// ---------------------------------------------------------------------------
// K0: W [k][n] fp32 -> Wt [n][k] f16 (plain transpose, k-contiguous rows).
// Fused kernel reads Wt directly from global (L2-resident), so no swizzle.
// ---------------------------------------------------------------------------
__global__ __launch_bounds__(1024) void k_transpose(const float* __restrict__ W,
                                                    f16* __restrict__ Wt) {
  __shared__ float t[32][33];
  const int tx = threadIdx.x, ty = threadIdx.y;
  const int n0 = blockIdx.x * 32, k0 = blockIdx.y * 32;
  t[ty][tx] = W[(size_t)(k0 + ty) * DDIM + n0 + tx];
  __syncthreads();
  const int n = n0 + ty, k = k0 + tx;
  Wt[(size_t)n * DDIM + k] = (f16)t[tx][ty];
}

// ---------------------------------------------------------------------------
// K1: fully fused  out = sparsemax( ghostBN(A @ W) * priors ).
// 1 block/CU (reg-capped: 64 AGPR acc + ~60 VGPR = 4 waves/SIMD).
// R2 lesson: __syncthreads() drains vmcnt(0) -> any per-K-step barrier
// serializes loads against compute. This version needs NO K-loop barriers:
//  * A staged ONCE into LDS as f16 (128x512 = 128 KB, chunk-XOR-swizzled so
//    ds_read_b128 fragments are bank-uniform), one barrier after staging.
//    A's HBM read IS the staging: BW-optimal, deeply pipelined by compiler.
//  * B read directly from global Wt per wave (disjoint 32-col slices ->
//    each element read once per block; Wt 512KB is L2-resident since all
//    blocks share it). Zero LDS, zero barrier, compiler-counted waits.
//  * K-loop: pure ds_read + global_load + MFMA, address math folds into
//    immediate offsets; waves self-pace across all 16 steps.
// Epilogue: 8 passes x 16 rows; dbuf LDS transpose (overlays A region),
// DPP reductions, priors hoisted above the pass barrier, max-init Michelot.
// ---------------------------------------------------------------------------
__global__ __launch_bounds__(1024, 4) void k_fused(
    const float* __restrict__ A, const float* __restrict__ priors,
    const f16*  __restrict__ Bt, const float* __restrict__ gamma,
    const float* __restrict__ beta, float* __restrict__ Out) {
  __shared__ __align__(16) char smem[131072];
  f16*   Ash = (f16*)smem;              // [128][512] f16 = 128 KB (K-loop)
  float* zb0 = (float*)smem;            // [16][516] f32 = 33 KB (epilogue)
  float* zb1 = (float*)(smem + 33024);  // 33 KB (dbuf; overlays Ash)

  const int tid  = threadIdx.x;
  const int lane = tid & 63;
  const int wid  = tid >> 6;           // 0..15: wave = 32-col slice
  const int lr   = lane & 15;
  const int lq   = lane >> 4;
  const int m0   = blockIdx.x * BM;

  f32x4 acc[8][2];
#pragma unroll
  for (int mi = 0; mi < 8; ++mi)
#pragma unroll
    for (int ni = 0; ni < 2; ++ni) acc[mi][ni] = (f32x4){0.f, 0.f, 0.f, 0.f};

  // ---- stage A once: fp32 global (coalesced 32B/lane) -> f16 LDS ----------
  // element (row,k): chunk kc=k>>3 stored at (kc&~7)|((kc&7)^(row&7)) so the
  // K-loop's 64-lane ds_read_b128 pattern spreads across all bank quads.
#pragma unroll
  for (int it = 0; it < 8; ++it) {
    const int c   = it * 1024 + tid;    // 8192 chunks = 128 rows x 64 chunks
    const int row = c >> 6, kc = c & 63;
    const float* g = A + (size_t)(m0 + row) * DDIM + kc * 8;
    const float4 a0 = *(const float4*)g;
    const float4 a1 = *(const float4*)(g + 4);
    f16x8 h = {(f16)a0.x, (f16)a0.y, (f16)a0.z, (f16)a0.w,
               (f16)a1.x, (f16)a1.y, (f16)a1.z, (f16)a1.w};
    const int sc = (kc & ~7) | ((kc & 7) ^ (row & 7));
    *(f16x8*)(Ash + (size_t)row * DDIM + sc * 8) = h;
  }
  __syncthreads();                      // the ONLY pre-epilogue barrier

  // ---- K-loop: no barriers, no LDS writes, immediate-offset addressing ----
  const f16* bt0 = Bt + (size_t)(wid * 32 + lr) * DDIM + lq * 8;
  const f16* bt1 = bt0 + (size_t)16 * DDIM;
  const f16* a_base = Ash + (size_t)lr * DDIM;

#pragma unroll 4
  for (int ks = 0; ks < 16; ++ks) {
    const f16x8 bf0 = *(const f16x8*)(bt0 + ks * 32);
    const f16x8 bf1 = *(const f16x8*)(bt1 + ks * 32);
    const int kc = ks * 4 + lq;
    const int sc = (kc & ~7) | ((kc & 7) ^ (lr & 7));
#pragma unroll
    for (int mi = 0; mi < 8; ++mi) {
      const f16x8 af = *(const f16x8*)(a_base + (size_t)mi * 16 * DDIM + sc * 8);
      acc[mi][0] = __builtin_amdgcn_mfma_f32_16x16x32_f16(af, bf0, acc[mi][0], 0, 0, 0);
      acc[mi][1] = __builtin_amdgcn_mfma_f32_16x16x32_f16(af, bf1, acc[mi][1], 0, 0, 0);
    }
  }

  // --- ghost-BN stats in-wave (wave owns whole columns) + apply ---
  // C/D layout: col = lane&15 (per 16-tile), row = mi*16 + lq*4 + r
#pragma unroll
  for (int ni = 0; ni < 2; ++ni) {
    float ps = 0.f, pq = 0.f;
#pragma unroll
    for (int mi = 0; mi < 8; ++mi)
#pragma unroll
      for (int r = 0; r < 4; ++r) {
        const float v = acc[mi][ni][r];
        ps += v; pq += v * v;
      }
    ps += __shfl_xor(ps, 16); ps += __shfl_xor(ps, 32);  // sum over lq
    pq += __shfl_xor(pq, 16); pq += __shfl_xor(pq, 32);
    const int col = wid * 32 + ni * 16 + lr;
    const float mean = ps * (1.f / 128.f);
    const float var  = pq * (1.f / 128.f) - mean * mean;
    const float rstd = rsqrtf(var + 1e-3f);
    const float s = rstd * gamma[col];
    const float b = beta[col] - mean * s;
#pragma unroll
    for (int mi = 0; mi < 8; ++mi)
#pragma unroll
      for (int r = 0; r < 4; ++r)
        acc[mi][ni][r] = acc[mi][ni][r] * s + b;
  }

  __syncthreads();   // all waves done reading Ash -> zb may overlay it

  // --- epilogue: 8 passes x 16 rows; dbuf LDS transpose, 1 barrier/pass ---
  const float* pr_base = priors + (size_t)(m0 + wid) * DDIM;
  float* out_base = Out + (size_t)(m0 + wid) * DDIM;
#pragma unroll
  for (int p = 0; p < 8; ++p) {
    float* zbc = (p & 1) ? zb1 : zb0;
    // dump rows p*16..p*16+15 (mi = p): 2-way-max bank aliasing (free)
#pragma unroll
    for (int ni = 0; ni < 2; ++ni)
#pragma unroll
      for (int r = 0; r < 4; ++r)
        zbc[(lq * 4 + r) * ZP + wid * 32 + ni * 16 + lr] = acc[p][ni][r];

    // hoist priors (HBM ~900cyc) above the barrier: hides under write+wait
    const float* pr = pr_base + (size_t)p * 16 * DDIM;
    const float4 pva = *(const float4*)(pr + lane * 4);
    const float4 pvb = *(const float4*)(pr + 256 + lane * 4);
    __syncthreads();

    // wave `wid` processes local row `wid`: 8 f32/lane, fully coalesced I/O
    const float4 zva = *(const float4*)(zbc + wid * ZP + lane * 4);
    const float4 zvb = *(const float4*)(zbc + wid * ZP + 256 + lane * 4);
    float z[8];
    z[0] = zva.x * pva.x; z[1] = zva.y * pva.y;
    z[2] = zva.z * pva.z; z[3] = zva.w * pva.w;
    z[4] = zvb.x * pvb.x; z[5] = zvb.y * pvb.y;
    z[6] = zvb.z * pvb.z; z[7] = zvb.w * pvb.w;
    float M = fmaxf(fmaxf(fmaxf(z[0], z[1]), fmaxf(z[2], z[3])),
                    fmaxf(fmaxf(z[4], z[5]), fmaxf(z[6], z[7])));
    // tau* >= zmax - 1; Michelot from tau0 <= tau* is monotone-correct.
    M = dpp_max64(M);
    float tau = M - 1.f;
    unsigned rcprev = 0xFFFFFFFFu;
    for (int it = 0; it < 40; ++it) {        // converges in ~3-5 iters
      float rs = 0.f;
      unsigned rc = 0;
#pragma unroll
      for (int j = 0; j < 8; ++j) {
        const bool a = z[j] > tau;
        rs += a ? z[j] : 0.f;
        rc += (unsigned)__popcll(__ballot(a));  // SALU count
        z[j] = a ? z[j] : -1e30f;               // knock out, never re-admit
      }
      rs = dpp_sum64(rs);                       // ~60cyc chain, uniform result
      if (rc == rcprev) break;                  // uniform scalar branch
      rcprev = rc;
      tau = (rs - 1.f) / (float)rc;             // rc >= 1 (max survives)
    }
    float* orow = out_base + (size_t)p * 16 * DDIM;
    float4 o;
    o.x = fmaxf(z[0] - tau, 0.f); o.y = fmaxf(z[1] - tau, 0.f);
    o.z = fmaxf(z[2] - tau, 0.f); o.w = fmaxf(z[3] - tau, 0.f);
    *(float4*)(orow + lane * 4) = o;
    o.x = fmaxf(z[4] - tau, 0.f); o.y = fmaxf(z[5] - tau, 0.f);
    o.z = fmaxf(z[6] - tau, 0.f); o.w = fmaxf(z[7] - tau, 0.f);
    *(float4*)(orow + 256 + lane * 4) = o;
  }
}

// ---------------------------------------------------------------------------
extern "C" void kernel_launch(void* const* d_in, const int* in_sizes, int n_in,
                              void* d_out, int out_size, void* d_ws, size_t ws_size,
                              hipStream_t stream) {
  const float* inputs = (const float*)d_in[0];
  const float* priors = (const float*)d_in[1];
  const float* W      = (const float*)d_in[2];
  const float* gamma  = (const float*)d_in[3];
  const float* beta   = (const float*)d_in[4];
  float* out = (float*)d_out;
  f16*   Wt  = (f16*)d_ws;                   // 512 KB scratch

  hipLaunchKernelGGL(k_transpose, dim3(DDIM / 32, DDIM / 32), dim3(32, 32), 0, stream, W, Wt);
  hipLaunchKernelGGL(k_fused, dim3(NROWS / BM), dim3(1024), 0, stream,
                     inputs, priors, Wt, gamma, beta, out);
}